// Round 4
// baseline (170.003 us; speedup 1.0000x reference)
//
#include <hip/hip_runtime.h>

#define B_ 32
#define T_ 4096
#define D_ 256
#define A_ 128

typedef __attribute__((ext_vector_type(8))) short bf16x8;
typedef __attribute__((ext_vector_type(4))) float f32x4;

__device__ __forceinline__ ushort f32_to_bf16_rne(float x) {
    uint u = __float_as_uint(x);
    u = (u + 0x7FFFu + ((u >> 16) & 1u)) >> 16;
    return (ushort)u;
}
__device__ __forceinline__ float bf16_bits_to_f32(ushort b) {
    return __uint_as_float(((uint)b) << 16);
}

// -----------------------------------------------------------------------------
// Kernel 0: W [A][D] fp32 -> hi/lo bf16 planes (RNE hi, residual lo).
// -----------------------------------------------------------------------------
__global__ __launch_bounds__(256) void convert_W_kernel(
    const float* __restrict__ W, ushort* __restrict__ Whi, ushort* __restrict__ Wlo)
{
    const int i = blockIdx.x * 256 + threadIdx.x;
    float x = W[i];
    ushort hb = f32_to_bf16_rne(x);
    Whi[i] = hb;
    Wlo[i] = f32_to_bf16_rne(x - bf16_bits_to_f32(hb));
}

// fast tanh: 1 - 2/(e^{2x}+1). Handles +-inf of exp correctly (-> +-1).
__device__ __forceinline__ float fast_tanh(float x) {
    float t = __expf(2.0f * x);
    float r = __builtin_amdgcn_rcpf(t + 1.0f);
    return fmaf(-2.0f, r, 1.0f);
}

// split 8 f32 -> hi bf16x8 (round-half-up) + lo bf16x8 (exact residual, trunc)
// 8 VALU ops per pair via v_perm packing.
__device__ __forceinline__ void split8(float4 a, float4 b, bf16x8& hi8, bf16x8& lo8) {
    float xs[8] = {a.x, a.y, a.z, a.w, b.x, b.y, b.z, b.w};
    union { uint w[4]; bf16x8 v; } H, L;
#pragma unroll
    for (int p = 0; p < 4; ++p) {
        float x0 = xs[2 * p], x1 = xs[2 * p + 1];
        uint r0 = __float_as_uint(x0) + 0x8000u;
        uint r1 = __float_as_uint(x1) + 0x8000u;
        H.w[p] = __builtin_amdgcn_perm(r1, r0, 0x07060302u);
        float rem0 = x0 - __uint_as_float(r0 & 0xFFFF0000u);  // exact
        float rem1 = x1 - __uint_as_float(r1 & 0xFFFF0000u);
        L.w[p] = __builtin_amdgcn_perm(__float_as_uint(rem1), __float_as_uint(rem0), 0x07060302u);
    }
    hi8 = H.v;
    lo8 = L.v;
}

// -----------------------------------------------------------------------------
// Kernel 1: score = sum_a tanh(h·W^T + bw)·uw via split-bf16 MFMA.
// Pure-register 2-iteration-deep h prefetch; issue order per iteration is
// [W loads][SB][h prefetch st+2][SB][split+MFMA][SB] so that every
// compiler-inserted vmcnt wait keeps the (youngest) h prefetches in flight.
// No LDS, no barriers. Block = 4 waves x 16 rows = 64 rows.
// -----------------------------------------------------------------------------
__global__ __launch_bounds__(256, 3) void score_mfma_kernel(
    const float* __restrict__ h,
    const ushort* __restrict__ Whi, const ushort* __restrict__ Wlo,
    const float* __restrict__ bw, const float* __restrict__ uw,
    float* __restrict__ score)
{
    const int tid  = threadIdx.x;
    const int w    = tid >> 6;
    const int lane = tid & 63;
    const int l15  = lane & 15;
    const int l4   = lane >> 4;
    const int rowbase = blockIdx.x * 64 + w * 16;

    const float* hrow = h + (size_t)(rowbase + l15) * D_ + l4 * 8;

    f32x4 acc[8];
#pragma unroll
    for (int j = 0; j < 8; ++j)
#pragma unroll
        for (int r = 0; r < 4; ++r) acc[j][r] = 0.f;

    float4 hbuf[8][2];   // fully unrolled loop -> only ~3 slots live

#define PREF(s)                                                             \
    {                                                                       \
        hbuf[s][0] = *reinterpret_cast<const float4*>(hrow + (s) * 32);     \
        hbuf[s][1] = *reinterpret_cast<const float4*>(hrow + (s) * 32 + 4); \
    }

    PREF(0);
    PREF(1);

#pragma unroll
    for (int st = 0; st < 8; ++st) {
        const int kb = st * 32 + l4 * 8;

        bf16x8 wh[8], wl[8];
#pragma unroll
        for (int j = 0; j < 8; ++j) {
            const size_t woff = (size_t)(j * 16 + l15) * D_ + kb;
            wh[j] = *reinterpret_cast<const bf16x8*>(Whi + woff);
            wl[j] = *reinterpret_cast<const bf16x8*>(Wlo + woff);
        }
        __builtin_amdgcn_sched_barrier(0);

        if (st < 6) { PREF(st + 2); }
        __builtin_amdgcn_sched_barrier(0);

        bf16x8 ahi, alo;
        split8(hbuf[st][0], hbuf[st][1], ahi, alo);

#pragma unroll
        for (int j = 0; j < 8; ++j) {
            acc[j] = __builtin_amdgcn_mfma_f32_16x16x32_bf16(ahi, wh[j], acc[j], 0, 0, 0);
            acc[j] = __builtin_amdgcn_mfma_f32_16x16x32_bf16(alo, wh[j], acc[j], 0, 0, 0);
            acc[j] = __builtin_amdgcn_mfma_f32_16x16x32_bf16(ahi, wl[j], acc[j], 0, 0, 0);
        }
        __builtin_amdgcn_sched_barrier(0);
    }
#undef PREF

    // epilogue: tanh + dot(uw) + 16-lane reduce
    float rsum[4] = {0.f, 0.f, 0.f, 0.f};
#pragma unroll
    for (int j = 0; j < 8; ++j) {
        const float bwv = bw[j * 16 + l15];
        const float uwv = uw[j * 16 + l15];
#pragma unroll
        for (int r = 0; r < 4; ++r)
            rsum[r] = fmaf(fast_tanh(acc[j][r] + bwv), uwv, rsum[r]);
    }

#pragma unroll
    for (int r = 0; r < 4; ++r) {
#pragma unroll
        for (int m = 1; m < 16; m <<= 1)
            rsum[r] += __shfl_xor(rsum[r], m, 64);
    }

    if (l15 == 0) {
#pragma unroll
        for (int r = 0; r < 4; ++r)
            score[rowbase + l4 * 4 + r] = rsum[r];
    }
}

// -----------------------------------------------------------------------------
// Kernel 2: in-place softmax over T per batch.
// -----------------------------------------------------------------------------
__global__ __launch_bounds__(256) void softmax_kernel(float* __restrict__ score)
{
    const int b   = blockIdx.x;
    const int tid = threadIdx.x;
    float* row = score + (size_t)b * T_;

    __shared__ float sbuf[T_];
    __shared__ float red[256];

    float lmax = -3.0e38f;
    for (int t = tid; t < T_; t += 256) {
        float v = row[t];
        sbuf[t] = v;
        lmax = fmaxf(lmax, v);
    }
    red[tid] = lmax;
    __syncthreads();
    for (int s = 128; s > 0; s >>= 1) {
        if (tid < s) red[tid] = fmaxf(red[tid], red[tid + s]);
        __syncthreads();
    }
    const float m = red[0];
    __syncthreads();

    float lsum = 0.f;
    for (int t = tid; t < T_; t += 256) {
        float e = expf(sbuf[t] - m);
        sbuf[t] = e;
        lsum += e;
    }
    red[tid] = lsum;
    __syncthreads();
    for (int s = 128; s > 0; s >>= 1) {
        if (tid < s) red[tid] += red[tid + s];
        __syncthreads();
    }
    const float inv = 1.f / red[0];
    __syncthreads();

    for (int t = tid; t < T_; t += 256)
        row[t] = sbuf[t] * inv;
}

// -----------------------------------------------------------------------------
// Kernel 3/4: weighted pooling (partials, then reduce).
// -----------------------------------------------------------------------------
__global__ __launch_bounds__(256) void pool_partial_kernel(
    const float* __restrict__ h, const float* __restrict__ alpha,
    float* __restrict__ part)
{
    const int b = blockIdx.y;
    const int c = blockIdx.x;
    const int d = threadIdx.x;

    const float* hp = h + ((size_t)b * T_ + (size_t)c * 64) * D_ + d;
    const float* ap = alpha + (size_t)b * T_ + (size_t)c * 64;

    float acc = 0.f;
#pragma unroll 8
    for (int t = 0; t < 64; ++t)
        acc = fmaf(ap[t], hp[(size_t)t * D_], acc);

    part[((size_t)b * 64 + c) * D_ + d] = acc;
}

__global__ __launch_bounds__(256) void pool_reduce_kernel(
    const float* __restrict__ part, float* __restrict__ out)
{
    const int b = blockIdx.x;
    const int d = threadIdx.x;
    float acc = 0.f;
#pragma unroll 8
    for (int c = 0; c < 64; ++c)
        acc += part[((size_t)b * 64 + c) * D_ + d];
    out[(size_t)b * D_ + d] = acc;
}

extern "C" void kernel_launch(void* const* d_in, const int* in_sizes, int n_in,
                              void* d_out, int out_size, void* d_ws, size_t ws_size,
                              hipStream_t stream) {
    const float* h  = (const float*)d_in[0];
    const float* W  = (const float*)d_in[1];
    const float* bw = (const float*)d_in[2];
    const float* uw = (const float*)d_in[3];
    float* out = (float*)d_out;

    float*  score = (float*)d_ws;                         // 512 KB
    ushort* Whi   = (ushort*)(score + (size_t)B_ * T_);   // 64 KB
    ushort* Wlo   = Whi + (size_t)A_ * D_;                // 64 KB
    float*  part  = (float*)(Wlo + (size_t)A_ * D_);      // 2 MB

    convert_W_kernel<<<dim3((A_ * D_) / 256), 256, 0, stream>>>(W, Whi, Wlo);
    score_mfma_kernel<<<dim3((B_ * T_) / 64), 256, 0, stream>>>(h, Whi, Wlo, bw, uw, score);
    softmax_kernel<<<dim3(B_), 256, 0, stream>>>(score);
    pool_partial_kernel<<<dim3(64, B_), 256, 0, stream>>>(h, score, part);
    pool_reduce_kernel<<<dim3(B_), 256, 0, stream>>>(part, out);
}

// Round 5
// 72.646 us; speedup vs baseline: 2.3402x; 2.3402x over previous
//
#include <hip/hip_runtime.h>

#define B_ 32
#define T_ 4096
#define D_ 256
#define A_ 128

typedef __attribute__((ext_vector_type(8))) short bf16x8;
typedef __attribute__((ext_vector_type(4))) float f32x4;

__device__ __forceinline__ ushort f32_to_bf16_rne(float x) {
    uint u = __float_as_uint(x);
    u = (u + 0x7FFFu + ((u >> 16) & 1u)) >> 16;
    return (ushort)u;
}
__device__ __forceinline__ float bf16_bits_to_f32(ushort b) {
    return __uint_as_float(((uint)b) << 16);
}

// fast tanh: 1 - 2/(e^{2x}+1); exp inf -> +-1 handled naturally.
__device__ __forceinline__ float fast_tanh(float x) {
    float t = __expf(2.0f * x);
    float r = __builtin_amdgcn_rcpf(t + 1.0f);
    return fmaf(-2.0f, r, 1.0f);
}

// split 8 f32 -> hi bf16x8 (round-half-up) + lo bf16x8 (exact residual)
__device__ __forceinline__ void split8(float4 a, float4 b, bf16x8& hi8, bf16x8& lo8) {
    float xs[8] = {a.x, a.y, a.z, a.w, b.x, b.y, b.z, b.w};
    union { uint w[4]; bf16x8 v; } H, L;
#pragma unroll
    for (int p = 0; p < 4; ++p) {
        float x0 = xs[2 * p], x1 = xs[2 * p + 1];
        uint r0 = __float_as_uint(x0) + 0x8000u;
        uint r1 = __float_as_uint(x1) + 0x8000u;
        H.w[p] = __builtin_amdgcn_perm(r1, r0, 0x07060302u);
        float rem0 = x0 - __uint_as_float(r0 & 0xFFFF0000u);
        float rem1 = x1 - __uint_as_float(r1 & 0xFFFF0000u);
        L.w[p] = __builtin_amdgcn_perm(__float_as_uint(rem1), __float_as_uint(rem0), 0x07060302u);
    }
    hi8 = H.v;
    lo8 = L.v;
}

// -----------------------------------------------------------------------------
// Kernel 0: W [A][D] fp32 -> hi/lo bf16 planes.
// -----------------------------------------------------------------------------
__global__ __launch_bounds__(256) void convert_W_kernel(
    const float* __restrict__ W, ushort* __restrict__ Whi, ushort* __restrict__ Wlo)
{
    const int i = blockIdx.x * 256 + threadIdx.x;
    float x = W[i];
    ushort hb = f32_to_bf16_rne(x);
    Whi[i] = hb;
    Wlo[i] = f32_to_bf16_rne(x - bf16_bits_to_f32(hb));
}

// -----------------------------------------------------------------------------
// Kernel 1: score = sum_a tanh(h·W^T + bw)·uw  via split-bf16 MFMA.
// W fragments live in LDS (ds_read -> lgkmcnt), so vmcnt carries ONLY the
// in-order h prefetch stream; compiler per-register waits keep younger h
// loads in flight. W staged in two 64KB K-phases (k 0..127 / 128..255).
// LDS layout per plane: [128 rows][16 slots of 16B], slot ^= (row&7) swizzle.
// Block = 4 waves x 32 rows = 128 rows; grid 1024; 2 blocks/CU.
// -----------------------------------------------------------------------------
__global__ __launch_bounds__(256, 2) void score_mfma_kernel(
    const float* __restrict__ h,
    const ushort* __restrict__ Whi, const ushort* __restrict__ Wlo,
    const float* __restrict__ bw, const float* __restrict__ uw,
    float* __restrict__ score)
{
    __shared__ char wlds[65536];   // [plane][row][swizzled slot]

    const int tid  = threadIdx.x;
    const int w    = tid >> 6;
    const int lane = tid & 63;
    const int l15  = lane & 15;
    const int l4   = lane >> 4;
    const int rowbase = blockIdx.x * 128 + w * 32;

    const float* hrow0 = h + (size_t)(rowbase + l15) * D_ + l4 * 8;
    const float* hrow1 = hrow0 + 16 * D_;

    f32x4 acc[2][8];
#pragma unroll
    for (int rt = 0; rt < 2; ++rt)
#pragma unroll
        for (int j = 0; j < 8; ++j)
#pragma unroll
            for (int r = 0; r < 4; ++r) acc[rt][j][r] = 0.f;

    float4 hbuf[8][2][2];   // [stg][rt][half]; ~3 slots live (full unroll)

#define PREF(s)                                                              \
    {                                                                        \
        hbuf[s][0][0] = *reinterpret_cast<const float4*>(hrow0 + (s) * 32);  \
        hbuf[s][0][1] = *reinterpret_cast<const float4*>(hrow0 + (s) * 32 + 4); \
        hbuf[s][1][0] = *reinterpret_cast<const float4*>(hrow1 + (s) * 32);  \
        hbuf[s][1][1] = *reinterpret_cast<const float4*>(hrow1 + (s) * 32 + 4); \
    }

    PREF(0);
    PREF(1);

#pragma unroll
    for (int ph = 0; ph < 2; ++ph) {
        // ---- stage 64 KB of W (both planes, K-half ph) into LDS ----
#pragma unroll
        for (int p = 0; p < 2; ++p) {
            const ushort* src = p ? Wlo : Whi;
#pragma unroll
            for (int i = 0; i < 8; ++i) {
                const int c    = i * 256 + tid;     // 16B-chunk id, 0..2047
                const int row  = c >> 4;            // 0..127
                const int slot = c & 15;
                float4 v = *reinterpret_cast<const float4*>(
                    src + (size_t)row * D_ + ph * 128 + slot * 8);
                *reinterpret_cast<float4*>(
                    wlds + p * 32768 + row * 256 + ((slot ^ (row & 7)) << 4)) = v;
            }
        }
        __syncthreads();

#pragma unroll
        for (int st = 0; st < 4; ++st) {
            const int stg = ph * 4 + st;
            if (stg < 6) PREF(stg + 2);

            bf16x8 ahi[2], alo[2];
            split8(hbuf[stg][0][0], hbuf[stg][0][1], ahi[0], alo[0]);
            split8(hbuf[stg][1][0], hbuf[stg][1][1], ahi[1], alo[1]);

            const int slotbase = st * 4 + l4;
#pragma unroll
            for (int j = 0; j < 8; ++j) {
                const int row = j * 16 + l15;
                const int off = row * 256 + ((slotbase ^ (row & 7)) << 4);
                bf16x8 wh = *reinterpret_cast<const bf16x8*>(wlds + off);
                bf16x8 wl = *reinterpret_cast<const bf16x8*>(wlds + 32768 + off);
#pragma unroll
                for (int rt = 0; rt < 2; ++rt) {
                    acc[rt][j] = __builtin_amdgcn_mfma_f32_16x16x32_bf16(ahi[rt], wh, acc[rt][j], 0, 0, 0);
                    acc[rt][j] = __builtin_amdgcn_mfma_f32_16x16x32_bf16(alo[rt], wh, acc[rt][j], 0, 0, 0);
                    acc[rt][j] = __builtin_amdgcn_mfma_f32_16x16x32_bf16(ahi[rt], wl, acc[rt][j], 0, 0, 0);
                }
            }
        }
        if (ph == 0) __syncthreads();   // all waves done reading before restage
    }
#undef PREF

    // ---- epilogue: tanh + dot(uw) + 16-lane reduce ----
    float rsum[2][4];
#pragma unroll
    for (int rt = 0; rt < 2; ++rt)
#pragma unroll
        for (int r = 0; r < 4; ++r) rsum[rt][r] = 0.f;

#pragma unroll
    for (int j = 0; j < 8; ++j) {
        const float bwv = bw[j * 16 + l15];
        const float uwv = uw[j * 16 + l15];
#pragma unroll
        for (int rt = 0; rt < 2; ++rt)
#pragma unroll
            for (int r = 0; r < 4; ++r)
                rsum[rt][r] = fmaf(fast_tanh(acc[rt][j][r] + bwv), uwv, rsum[rt][r]);
    }

#pragma unroll
    for (int rt = 0; rt < 2; ++rt)
#pragma unroll
        for (int r = 0; r < 4; ++r) {
#pragma unroll
            for (int m = 1; m < 16; m <<= 1)
                rsum[rt][r] += __shfl_xor(rsum[rt][r], m, 64);
        }

    if (l15 == 0) {
#pragma unroll
        for (int rt = 0; rt < 2; ++rt)
#pragma unroll
            for (int r = 0; r < 4; ++r)
                score[rowbase + rt * 16 + l4 * 4 + r] = rsum[rt][r];
    }
}

// -----------------------------------------------------------------------------
// Kernel 2: in-place softmax over T per batch.
// -----------------------------------------------------------------------------
__global__ __launch_bounds__(256) void softmax_kernel(float* __restrict__ score)
{
    const int b   = blockIdx.x;
    const int tid = threadIdx.x;
    float* row = score + (size_t)b * T_;

    __shared__ float sbuf[T_];
    __shared__ float red[256];

    float lmax = -3.0e38f;
    for (int t = tid; t < T_; t += 256) {
        float v = row[t];
        sbuf[t] = v;
        lmax = fmaxf(lmax, v);
    }
    red[tid] = lmax;
    __syncthreads();
    for (int s = 128; s > 0; s >>= 1) {
        if (tid < s) red[tid] = fmaxf(red[tid], red[tid + s]);
        __syncthreads();
    }
    const float m = red[0];
    __syncthreads();

    float lsum = 0.f;
    for (int t = tid; t < T_; t += 256) {
        float e = expf(sbuf[t] - m);
        sbuf[t] = e;
        lsum += e;
    }
    red[tid] = lsum;
    __syncthreads();
    for (int s = 128; s > 0; s >>= 1) {
        if (tid < s) red[tid] += red[tid + s];
        __syncthreads();
    }
    const float inv = 1.f / red[0];
    __syncthreads();

    for (int t = tid; t < T_; t += 256)
        row[t] = sbuf[t] * inv;
}

// -----------------------------------------------------------------------------
// Kernel 3: pooling partials, float4-vectorized. Block (c,b): 64 t-rows.
// tid -> (tr = row subgroup 0..3, d4 = float4 column 0..63).
// -----------------------------------------------------------------------------
__global__ __launch_bounds__(256) void pool_partial_kernel(
    const float* __restrict__ h, const float* __restrict__ alpha,
    float* __restrict__ part)
{
    const int b  = blockIdx.y;
    const int c  = blockIdx.x;
    const int d4 = threadIdx.x & 63;
    const int tr = threadIdx.x >> 6;

    __shared__ float  alds[64];
    __shared__ float4 red[4][64];

    if (threadIdx.x < 64)
        alds[threadIdx.x] = alpha[(size_t)b * T_ + c * 64 + threadIdx.x];
    __syncthreads();

    const float* hp = h + ((size_t)b * T_ + (size_t)c * 64) * D_;
    float4 acc = {0.f, 0.f, 0.f, 0.f};
#pragma unroll
    for (int i = 0; i < 16; ++i) {
        const int r = i * 4 + tr;
        float4 v = *reinterpret_cast<const float4*>(hp + (size_t)r * D_ + d4 * 4);
        const float a = alds[r];
        acc.x = fmaf(a, v.x, acc.x);
        acc.y = fmaf(a, v.y, acc.y);
        acc.z = fmaf(a, v.z, acc.z);
        acc.w = fmaf(a, v.w, acc.w);
    }
    red[tr][d4] = acc;
    __syncthreads();
    if (tr == 0) {
        float4 s0 = red[0][d4], s1 = red[1][d4], s2 = red[2][d4], s3 = red[3][d4];
        float4 o = {s0.x + s1.x + s2.x + s3.x, s0.y + s1.y + s2.y + s3.y,
                    s0.z + s1.z + s2.z + s3.z, s0.w + s1.w + s2.w + s3.w};
        *reinterpret_cast<float4*>(part + ((size_t)b * 64 + c) * D_ + d4 * 4) = o;
    }
}

// -----------------------------------------------------------------------------
// Kernel 4: reduce 64 partials -> out[b][d], float4-vectorized.
// -----------------------------------------------------------------------------
__global__ __launch_bounds__(256) void pool_reduce_kernel(
    const float* __restrict__ part, float* __restrict__ out)
{
    const int b  = blockIdx.x;
    const int d4 = threadIdx.x & 63;
    const int cc = threadIdx.x >> 6;

    __shared__ float4 red[4][64];

    float4 acc = {0.f, 0.f, 0.f, 0.f};
#pragma unroll
    for (int i = 0; i < 16; ++i) {
        float4 v = *reinterpret_cast<const float4*>(
            part + ((size_t)b * 64 + i * 4 + cc) * D_ + d4 * 4);
        acc.x += v.x; acc.y += v.y; acc.z += v.z; acc.w += v.w;
    }
    red[cc][d4] = acc;
    __syncthreads();
    if (cc == 0) {
        float4 s0 = red[0][d4], s1 = red[1][d4], s2 = red[2][d4], s3 = red[3][d4];
        float4 o = {s0.x + s1.x + s2.x + s3.x, s0.y + s1.y + s2.y + s3.y,
                    s0.z + s1.z + s2.z + s3.z, s0.w + s1.w + s2.w + s3.w};
        *reinterpret_cast<float4*>(out + (size_t)b * D_ + d4 * 4) = o;
    }
}

extern "C" void kernel_launch(void* const* d_in, const int* in_sizes, int n_in,
                              void* d_out, int out_size, void* d_ws, size_t ws_size,
                              hipStream_t stream) {
    const float* h  = (const float*)d_in[0];
    const float* W  = (const float*)d_in[1];
    const float* bw = (const float*)d_in[2];
    const float* uw = (const float*)d_in[3];
    float* out = (float*)d_out;

    float*  score = (float*)d_ws;                         // 512 KB
    ushort* Whi   = (ushort*)(score + (size_t)B_ * T_);   // 64 KB
    ushort* Wlo   = Whi + (size_t)A_ * D_;                // 64 KB
    float*  part  = (float*)(Wlo + (size_t)A_ * D_);      // 2 MB

    convert_W_kernel<<<dim3((A_ * D_) / 256), 256, 0, stream>>>(W, Whi, Wlo);
    score_mfma_kernel<<<dim3((B_ * T_) / 128), 256, 0, stream>>>(h, Whi, Wlo, bw, uw, score);
    softmax_kernel<<<dim3(B_), 256, 0, stream>>>(score);
    pool_partial_kernel<<<dim3(64, B_), 256, 0, stream>>>(h, score, part);
    pool_reduce_kernel<<<dim3(B_), 256, 0, stream>>>(part, out);
}